// Round 2
// baseline (187.299 us; speedup 1.0000x reference)
//
#include <hip/hip_runtime.h>
#include <math.h>

// Problem constants
#define NT 320
#define NS 16
#define PIN 8
#define MOUT 8
// step = TMAX/(NT-1)
#define STEPF (1.0f/319.0f)

// ---------------------------------------------------------------------------
// Kernel 1: build A (16x16) from V1_raw,V2_raw,V3_raw.  Single block, 256 thr.
//   V1 = tril(V1r,-1) + diag(|diag(V1r)|) + eps I ; M = V1 + eps I (lower-tri)
//   Minv by forward substitution (per-column, 16 threads)
//   P_inv = Minv^T Minv ;  W = -0.5 V2 V2^T + V3 ;  A = P_inv W
//   also write ||A||_inf for expm scaling
// ---------------------------------------------------------------------------
__global__ void k_build_A(const float* __restrict__ V1r,
                          const float* __restrict__ V2r,
                          const float* __restrict__ V3r,
                          float* __restrict__ A_out,
                          float* __restrict__ normA_out) {
    __shared__ float M[16][16];
    __shared__ float Minv[16][16];
    __shared__ float Pinv[16][16];
    __shared__ float W[16][16];
    __shared__ float V2[16][16];
    __shared__ float A_s[16][16];
    __shared__ float rowsum[16];
    const int tid = threadIdx.x;
    const int i = tid >> 4, j = tid & 15;

    float v;
    if (i > j)       v = V1r[i * 16 + j];
    else if (i == j) v = fabsf(V1r[i * 16 + i]) + 2.0f * 1e-3f;  // eps twice
    else             v = 0.0f;
    M[i][j]  = v;
    V2[i][j] = (j <= i) ? V2r[i * 16 + j] : 0.0f;
    __syncthreads();

    if (tid < 16) {  // forward substitution, column tid
        const int c = tid;
        float x[16];
        for (int r = 0; r < 16; ++r) {
            if (r < c) { x[r] = 0.0f; continue; }
            float s = (r == c) ? 1.0f : 0.0f;
            for (int k = c; k < r; ++k) s -= M[r][k] * x[k];
            x[r] = s / M[r][r];
        }
        for (int r = 0; r < 16; ++r) Minv[r][c] = x[r];
    }
    __syncthreads();

    {   // P_inv = Minv^T Minv
        float acc = 0.0f;
#pragma unroll
        for (int k = 0; k < 16; ++k) acc += Minv[k][i] * Minv[k][j];
        Pinv[i][j] = acc;
    }
    {   // W = -0.5 V2 V2^T + V3 (V3 = triu(V3r,1) - triu(V3r,1)^T)
        float acc = 0.0f;
#pragma unroll
        for (int k = 0; k < 16; ++k) acc += V2[i][k] * V2[j][k];
        float v3 = 0.0f;
        if (j > i)      v3 =  V3r[i * 16 + j];
        else if (i > j) v3 = -V3r[j * 16 + i];
        W[i][j] = -0.5f * acc + v3;
    }
    __syncthreads();
    {   // A = P_inv @ W
        float acc = 0.0f;
#pragma unroll
        for (int k = 0; k < 16; ++k) acc += Pinv[i][k] * W[k][j];
        A_s[i][j] = acc;
        A_out[tid] = acc;
    }
    __syncthreads();
    if (j == 0) {
        float r = 0.0f;
#pragma unroll
        for (int k = 0; k < 16; ++k) r += fabsf(A_s[i][k]);
        rowsum[i] = r;
    }
    __syncthreads();
    if (tid == 0) {
        float m = 0.0f;
        for (int k = 0; k < 16; ++k) m = fmaxf(m, rowsum[k]);
        *normA_out = m;
    }
}

// ---------------------------------------------------------------------------
// Kernel 2: per time index k (one block each): E_k = expm(A * t_k) by
// scaling-and-squaring + Taylor-12 Horner (theta=0.25 -> remainder ~1e-18).
// Emit CE_k = C E_k (8x16), Mrow_k = CE_k covar_x0 (8x16), G_k = CE_k B (8x8),
// y1_k = CE_k x0 (8).
// ---------------------------------------------------------------------------
__global__ void k_expm(const float* __restrict__ A_g,
                       const float* __restrict__ normA_g,
                       const float* __restrict__ C_w,
                       const float* __restrict__ B_w,
                       const float* __restrict__ cov0,
                       const float* __restrict__ x0,
                       float* __restrict__ CE_g,
                       float* __restrict__ Mrow_g,
                       float* __restrict__ G_g,
                       float* __restrict__ y1_g) {
    __shared__ float Bs[16][16];
    __shared__ float P[16][16];
    __shared__ float Cs[8][16];
    __shared__ float Bw[16][8];
    __shared__ float cov[16][16];
    __shared__ float x0s[16];
    __shared__ float CEs[8][16];
    const int tid = threadIdx.x;
    const int i = tid >> 4, j = tid & 15;
    const int k = blockIdx.x;
    const float t = (float)k * STEPF;

    const float a = A_g[tid];
    cov[i][j] = cov0[tid];
    if (tid < 128) Cs[tid >> 4][tid & 15] = C_w[tid];
    if (tid < 128) Bw[tid >> 3][tid & 7]  = B_w[tid];
    if (tid < 16)  x0s[tid] = x0[tid];

    // scaling: ||A t / 2^s||_inf <= 0.25
    float nt = (*normA_g) * t;
    int s = 0;
    while (nt > 0.25f && s < 30) { nt *= 0.5f; ++s; }
    const float scale = t * exp2f((float)(-s));
    Bs[i][j] = a * scale;
    __syncthreads();

    // Horner: E = I + B(I + B/2(I + ... (I + B/12)...))
    P[i][j] = ((i == j) ? 1.0f : 0.0f) + Bs[i][j] * (1.0f / 12.0f);
    __syncthreads();
    for (int d = 11; d >= 1; --d) {
        float acc = 0.0f;
#pragma unroll
        for (int kk = 0; kk < 16; ++kk) acc += Bs[i][kk] * P[kk][j];
        __syncthreads();
        P[i][j] = ((i == j) ? 1.0f : 0.0f) + acc / (float)d;
        __syncthreads();
    }
    // squarings
    for (int q = 0; q < s; ++q) {
        float acc = 0.0f;
#pragma unroll
        for (int kk = 0; kk < 16; ++kk) acc += P[i][kk] * P[kk][j];
        __syncthreads();
        P[i][j] = acc;
        __syncthreads();
    }

    // CE = C @ E  (8x16)
    if (tid < 128) {
        const int a8 = tid >> 4, jc = tid & 15;
        float acc = 0.0f;
#pragma unroll
        for (int kk = 0; kk < 16; ++kk) acc += Cs[a8][kk] * P[kk][jc];
        CEs[a8][jc] = acc;
        CE_g[k * 128 + tid] = acc;
    }
    __syncthreads();
    // Mrow = CE @ covar_x0  (8x16)
    if (tid < 128) {
        const int a8 = tid >> 4, l = tid & 15;
        float acc = 0.0f;
#pragma unroll
        for (int kk = 0; kk < 16; ++kk) acc += CEs[a8][kk] * cov[kk][l];
        Mrow_g[k * 128 + tid] = acc;
    }
    // G = CE @ B_w  (8x8)
    if (tid < 64) {
        const int a8 = tid >> 3, p = tid & 7;
        float acc = 0.0f;
#pragma unroll
        for (int kk = 0; kk < 16; ++kk) acc += CEs[a8][kk] * Bw[kk][p];
        G_g[k * 64 + tid] = acc;
    }
    // y1 = CE @ x0  (8)
    if (tid < 8) {
        float acc = 0.0f;
#pragma unroll
        for (int kk = 0; kk < 16; ++kk) acc += CEs[tid][kk] * x0s[kk];
        y1_g[k * 8 + tid] = acc;
    }
}

// ---------------------------------------------------------------------------
// Kernel 3: mean_y[i,m] = y1[i,m] + step * sum_{j<=i} w_j (G_{i-j} U_j)[m]
//                       + (D dU_i)[m].   One thread per (i,m): 2560 threads.
// ---------------------------------------------------------------------------
__global__ void k_mean(const float* __restrict__ y1_g,
                       const float* __restrict__ G_g,
                       const float* __restrict__ U,
                       const float* __restrict__ dU,
                       const float* __restrict__ D_w,
                       float* __restrict__ out_mean) {
    const int gid = blockIdx.x * 64 + threadIdx.x;  // 0..2559
    const int i = gid >> 3, mo = gid & 7;
    float acc = 0.0f;
    if (i > 0) {
        for (int j = 0; j <= i; ++j) {
            const float w = ((j == 0) || (j == i)) ? 0.5f : 1.0f;
            const float* Gr = G_g + (i - j) * 64 + mo * 8;
            const float* Ur = U + j * 8;
            float d = 0.0f;
#pragma unroll
            for (int p = 0; p < 8; ++p) d += Gr[p] * Ur[p];
            acc += w * d;
        }
    }
    float t3 = 0.0f;
#pragma unroll
    for (int p = 0; p < 8; ++p) t3 += D_w[mo * 8 + p] * dU[i * 8 + p];
    out_mean[gid] = y1_g[gid] + STEPF * acc + t3;
}

// ---------------------------------------------------------------------------
// Kernel 4: covar1[i,j,a,b] = Mrow_i[a,:] . CE_j[b,:]   (+ covar_U fused)
// Block = (jg in 0..19, i in 0..319); covers 16 j per block; float4 stores.
// ---------------------------------------------------------------------------
__global__ void k_covar(const float* __restrict__ Mrow_g,
                        const float* __restrict__ CE_g,
                        float* __restrict__ out_c1,
                        float* __restrict__ out_cu) {
    __shared__ float Mi[128];
    __shared__ float CEj[2048];
    const int tid = threadIdx.x;
    const int jg = blockIdx.x;   // 0..19
    const int i  = blockIdx.y;   // 0..319
    if (tid < 128) Mi[tid] = Mrow_g[i * 128 + tid];
    for (int idx = tid; idx < 2048; idx += 256) CEj[idx] = CE_g[jg * 2048 + idx];
    __syncthreads();

    const int jj = tid >> 4;         // 0..15
    const int a  = (tid >> 1) & 7;   // 0..7
    const int bg = tid & 1;          // 0..1 (4 b's each)
    const float* mi = Mi + a * 16;
    const float* ce = CEj + jj * 128 + bg * 64;
    float r[4];
#pragma unroll
    for (int b = 0; b < 4; ++b) {
        float acc = 0.0f;
#pragma unroll
        for (int l = 0; l < 16; ++l) acc += mi[l] * ce[b * 16 + l];
        r[b] = acc;
    }
    const int j = jg * 16 + jj;
    float4* dst = (float4*)(out_c1 + ((size_t)(i * 320 + j)) * 64 + a * 8 + bg * 4);
    *dst = make_float4(r[0], r[1], r[2], r[3]);

    if (tid < 16) {
        const int jx = jg * 16 + tid;
        const float d = (float)(i - jx) * STEPF;
        out_cu[i * 320 + jx] = expf(-50.0f * d * d);  // LT=0.1 -> 1/(2 LT^2)=50
    }
}

// ---------------------------------------------------------------------------
extern "C" void kernel_launch(void* const* d_in, const int* in_sizes, int n_in,
                              void* d_out, int out_size, void* d_ws, size_t ws_size,
                              hipStream_t stream) {
    const float* V1r  = (const float*)d_in[0];
    const float* V2r  = (const float*)d_in[1];
    const float* V3r  = (const float*)d_in[2];
    const float* B_w  = (const float*)d_in[3];
    const float* C_w  = (const float*)d_in[4];
    const float* D_w  = (const float*)d_in[5];
    const float* x0   = (const float*)d_in[6];
    const float* cov0 = (const float*)d_in[7];
    const float* U    = (const float*)d_in[8];
    const float* dU   = (const float*)d_in[9];

    float* ws    = (float*)d_ws;
    float* A     = ws;            // 256
    float* normA = ws + 256;      // 1 (padded to 512)
    float* CE    = ws + 512;      // 320*128 = 40960
    float* Mrow  = CE + 40960;    // 40960
    float* G     = Mrow + 40960;  // 320*64 = 20480
    float* y1    = G + 20480;     // 2560

    float* out      = (float*)d_out;
    float* out_mean = out;                      // 320*8
    float* out_c1   = out + 2560;               // 320*320*64
    float* out_cu   = out + 2560 + 320*320*64;  // 320*320

    k_build_A<<<1, 256, 0, stream>>>(V1r, V2r, V3r, A, normA);
    k_expm<<<NT, 256, 0, stream>>>(A, normA, C_w, B_w, cov0, x0, CE, Mrow, G, y1);
    k_mean<<<40, 64, 0, stream>>>(y1, G, U, dU, D_w, out_mean);
    k_covar<<<dim3(20, 320), 256, 0, stream>>>(Mrow, CE, out_c1, out_cu);
}

// Round 3
// 129.672 us; speedup vs baseline: 1.4444x; 1.4444x over previous
//
#include <hip/hip_runtime.h>
#include <math.h>

// Problem constants
#define NT 320
#define NS 16
#define PIN 8
#define MOUT 8
// step = TMAX/(NT-1)
#define STEPF (1.0f/319.0f)

// ---------------------------------------------------------------------------
// Kernel 1: build A (16x16) from V1_raw,V2_raw,V3_raw.  Single block, 256 thr.
// ---------------------------------------------------------------------------
__global__ void k_build_A(const float* __restrict__ V1r,
                          const float* __restrict__ V2r,
                          const float* __restrict__ V3r,
                          float* __restrict__ A_out,
                          float* __restrict__ normA_out) {
    __shared__ float M[16][16];
    __shared__ float Minv[16][16];
    __shared__ float Pinv[16][16];
    __shared__ float W[16][16];
    __shared__ float V2[16][16];
    __shared__ float A_s[16][16];
    __shared__ float rowsum[16];
    const int tid = threadIdx.x;
    const int i = tid >> 4, j = tid & 15;

    float v;
    if (i > j)       v = V1r[i * 16 + j];
    else if (i == j) v = fabsf(V1r[i * 16 + i]) + 2.0f * 1e-3f;  // eps twice
    else             v = 0.0f;
    M[i][j]  = v;
    V2[i][j] = (j <= i) ? V2r[i * 16 + j] : 0.0f;
    __syncthreads();

    if (tid < 16) {  // forward substitution, column tid
        const int c = tid;
        float x[16];
        for (int r = 0; r < 16; ++r) {
            if (r < c) { x[r] = 0.0f; continue; }
            float s = (r == c) ? 1.0f : 0.0f;
            for (int k = c; k < r; ++k) s -= M[r][k] * x[k];
            x[r] = s / M[r][r];
        }
        for (int r = 0; r < 16; ++r) Minv[r][c] = x[r];
    }
    __syncthreads();

    {   // P_inv = Minv^T Minv
        float acc = 0.0f;
#pragma unroll
        for (int k = 0; k < 16; ++k) acc += Minv[k][i] * Minv[k][j];
        Pinv[i][j] = acc;
    }
    {   // W = -0.5 V2 V2^T + V3
        float acc = 0.0f;
#pragma unroll
        for (int k = 0; k < 16; ++k) acc += V2[i][k] * V2[j][k];
        float v3 = 0.0f;
        if (j > i)      v3 =  V3r[i * 16 + j];
        else if (i > j) v3 = -V3r[j * 16 + i];
        W[i][j] = -0.5f * acc + v3;
    }
    __syncthreads();
    {   // A = P_inv @ W
        float acc = 0.0f;
#pragma unroll
        for (int k = 0; k < 16; ++k) acc += Pinv[i][k] * W[k][j];
        A_s[i][j] = acc;
        A_out[tid] = acc;
    }
    __syncthreads();
    if (j == 0) {
        float r = 0.0f;
#pragma unroll
        for (int k = 0; k < 16; ++k) r += fabsf(A_s[i][k]);
        rowsum[i] = r;
    }
    __syncthreads();
    if (tid == 0) {
        float m = 0.0f;
        for (int k = 0; k < 16; ++k) m = fmaxf(m, rowsum[k]);
        *normA_out = m;
    }
}

// ---------------------------------------------------------------------------
// Kernel 2: per time index k: E_k = expm(A * t_k), scaling-squaring Taylor-12.
// Emit CE_k (8x16), Mrow_k = CE_k cov0 (8x16), G_k = CE_k B (8x8), y1_k (8).
// ---------------------------------------------------------------------------
__global__ void k_expm(const float* __restrict__ A_g,
                       const float* __restrict__ normA_g,
                       const float* __restrict__ C_w,
                       const float* __restrict__ B_w,
                       const float* __restrict__ cov0,
                       const float* __restrict__ x0,
                       float* __restrict__ CE_g,
                       float* __restrict__ Mrow_g,
                       float* __restrict__ G_g,
                       float* __restrict__ y1_g) {
    __shared__ float Bs[16][16];
    __shared__ float P[16][16];
    __shared__ float Cs[8][16];
    __shared__ float Bw[16][8];
    __shared__ float cov[16][16];
    __shared__ float x0s[16];
    __shared__ float CEs[8][16];
    const int tid = threadIdx.x;
    const int i = tid >> 4, j = tid & 15;
    const int k = blockIdx.x;
    const float t = (float)k * STEPF;

    const float a = A_g[tid];
    cov[i][j] = cov0[tid];
    if (tid < 128) Cs[tid >> 4][tid & 15] = C_w[tid];
    if (tid < 128) Bw[tid >> 3][tid & 7]  = B_w[tid];
    if (tid < 16)  x0s[tid] = x0[tid];

    // scaling: ||A t / 2^s||_inf <= 0.25
    float nt = (*normA_g) * t;
    int s = 0;
    while (nt > 0.25f && s < 30) { nt *= 0.5f; ++s; }
    const float scale = t * exp2f((float)(-s));
    Bs[i][j] = a * scale;
    __syncthreads();

    // Horner: E = I + B(I + B/2(I + ... (I + B/12)...))
    P[i][j] = ((i == j) ? 1.0f : 0.0f) + Bs[i][j] * (1.0f / 12.0f);
    __syncthreads();
    for (int d = 11; d >= 1; --d) {
        float acc = 0.0f;
#pragma unroll
        for (int kk = 0; kk < 16; ++kk) acc += Bs[i][kk] * P[kk][j];
        __syncthreads();
        P[i][j] = ((i == j) ? 1.0f : 0.0f) + acc / (float)d;
        __syncthreads();
    }
    // squarings
    for (int q = 0; q < s; ++q) {
        float acc = 0.0f;
#pragma unroll
        for (int kk = 0; kk < 16; ++kk) acc += P[i][kk] * P[kk][j];
        __syncthreads();
        P[i][j] = acc;
        __syncthreads();
    }

    // CE = C @ E  (8x16)
    if (tid < 128) {
        const int a8 = tid >> 4, jc = tid & 15;
        float acc = 0.0f;
#pragma unroll
        for (int kk = 0; kk < 16; ++kk) acc += Cs[a8][kk] * P[kk][jc];
        CEs[a8][jc] = acc;
        CE_g[k * 128 + tid] = acc;
    }
    __syncthreads();
    // Mrow = CE @ covar_x0  (8x16)
    if (tid < 128) {
        const int a8 = tid >> 4, l = tid & 15;
        float acc = 0.0f;
#pragma unroll
        for (int kk = 0; kk < 16; ++kk) acc += CEs[a8][kk] * cov[kk][l];
        Mrow_g[k * 128 + tid] = acc;
    }
    // G = CE @ B_w  (8x8)
    if (tid < 64) {
        const int a8 = tid >> 3, p = tid & 7;
        float acc = 0.0f;
#pragma unroll
        for (int kk = 0; kk < 16; ++kk) acc += CEs[a8][kk] * Bw[kk][p];
        G_g[k * 64 + tid] = acc;
    }
    // y1 = CE @ x0  (8)
    if (tid < 8) {
        float acc = 0.0f;
#pragma unroll
        for (int kk = 0; kk < 16; ++kk) acc += CEs[tid][kk] * x0s[kk];
        y1_g[k * 8 + tid] = acc;
    }
}

// ---------------------------------------------------------------------------
// Kernel 3: mean_y[i,m].  One block per i (256 thr = 32 j-strides x 8 m).
// Thread (js,m) strides j by 32, float4 dots, LDS tree-reduce over js.
// 320 blocks x 4 waves = latency-hidden; G (80KB) + U (10KB) are L2-resident.
// ---------------------------------------------------------------------------
__global__ void k_mean(const float* __restrict__ y1_g,
                       const float* __restrict__ G_g,
                       const float* __restrict__ U,
                       const float* __restrict__ dU,
                       const float* __restrict__ D_w,
                       float* __restrict__ out_mean) {
    __shared__ float part[256];
    const int i   = blockIdx.x;        // 0..319
    const int tid = threadIdx.x;       // 0..255
    const int m   = tid & 7;
    const int js  = tid >> 3;          // 0..31
    float acc = 0.0f;
    if (i > 0) {
        for (int j = js; j <= i; j += 32) {
            const float w = ((j == 0) || (j == i)) ? 0.5f : 1.0f;
            const float4* Gr = (const float4*)(G_g + (i - j) * 64 + m * 8);
            const float4* Ur = (const float4*)(U + j * 8);
            const float4 g0 = Gr[0], g1 = Gr[1];
            const float4 u0 = Ur[0], u1 = Ur[1];
            float d = g0.x * u0.x + g0.y * u0.y + g0.z * u0.z + g0.w * u0.w
                    + g1.x * u1.x + g1.y * u1.y + g1.z * u1.z + g1.w * u1.w;
            acc += w * d;
        }
    }
    part[tid] = acc;
    __syncthreads();
#pragma unroll
    for (int off = 128; off >= 8; off >>= 1) {
        if (tid < off) part[tid] += part[tid + off];
        __syncthreads();
    }
    if (tid < 8) {
        float t3 = 0.0f;
#pragma unroll
        for (int p = 0; p < 8; ++p) t3 += D_w[tid * 8 + p] * dU[i * 8 + p];
        out_mean[i * 8 + tid] = y1_g[i * 8 + tid] + STEPF * part[tid] + t3;
    }
}

// ---------------------------------------------------------------------------
// Kernel 4: covar1[i,j,a,b] = Mrow_i[a,:] . CE_j[b,:]   (+ covar_U fused)
// ---------------------------------------------------------------------------
__global__ void k_covar(const float* __restrict__ Mrow_g,
                        const float* __restrict__ CE_g,
                        float* __restrict__ out_c1,
                        float* __restrict__ out_cu) {
    __shared__ float Mi[128];
    __shared__ float CEj[2048];
    const int tid = threadIdx.x;
    const int jg = blockIdx.x;   // 0..19
    const int i  = blockIdx.y;   // 0..319
    if (tid < 128) Mi[tid] = Mrow_g[i * 128 + tid];
    for (int idx = tid; idx < 2048; idx += 256) CEj[idx] = CE_g[jg * 2048 + idx];
    __syncthreads();

    const int jj = tid >> 4;         // 0..15
    const int a  = (tid >> 1) & 7;   // 0..7
    const int bg = tid & 1;          // 0..1 (4 b's each)
    const float* mi = Mi + a * 16;
    const float* ce = CEj + jj * 128 + bg * 64;
    float r[4];
#pragma unroll
    for (int b = 0; b < 4; ++b) {
        float acc = 0.0f;
#pragma unroll
        for (int l = 0; l < 16; ++l) acc += mi[l] * ce[b * 16 + l];
        r[b] = acc;
    }
    const int j = jg * 16 + jj;
    float4* dst = (float4*)(out_c1 + ((size_t)(i * 320 + j)) * 64 + a * 8 + bg * 4);
    *dst = make_float4(r[0], r[1], r[2], r[3]);

    if (tid < 16) {
        const int jx = jg * 16 + tid;
        const float d = (float)(i - jx) * STEPF;
        out_cu[i * 320 + jx] = expf(-50.0f * d * d);  // LT=0.1 -> 1/(2 LT^2)=50
    }
}

// ---------------------------------------------------------------------------
extern "C" void kernel_launch(void* const* d_in, const int* in_sizes, int n_in,
                              void* d_out, int out_size, void* d_ws, size_t ws_size,
                              hipStream_t stream) {
    const float* V1r  = (const float*)d_in[0];
    const float* V2r  = (const float*)d_in[1];
    const float* V3r  = (const float*)d_in[2];
    const float* B_w  = (const float*)d_in[3];
    const float* C_w  = (const float*)d_in[4];
    const float* D_w  = (const float*)d_in[5];
    const float* x0   = (const float*)d_in[6];
    const float* cov0 = (const float*)d_in[7];
    const float* U    = (const float*)d_in[8];
    const float* dU   = (const float*)d_in[9];

    float* ws    = (float*)d_ws;
    float* A     = ws;            // 256
    float* normA = ws + 256;      // 1 (padded to 512)
    float* CE    = ws + 512;      // 320*128 = 40960
    float* Mrow  = CE + 40960;    // 40960
    float* G     = Mrow + 40960;  // 320*64 = 20480
    float* y1    = G + 20480;     // 2560

    float* out      = (float*)d_out;
    float* out_mean = out;                      // 320*8
    float* out_c1   = out + 2560;               // 320*320*64
    float* out_cu   = out + 2560 + 320*320*64;  // 320*320

    k_build_A<<<1, 256, 0, stream>>>(V1r, V2r, V3r, A, normA);
    k_expm<<<NT, 256, 0, stream>>>(A, normA, C_w, B_w, cov0, x0, CE, Mrow, G, y1);
    k_mean<<<NT, 256, 0, stream>>>(y1, G, U, dU, D_w, out_mean);
    k_covar<<<dim3(20, 320), 256, 0, stream>>>(Mrow, CE, out_c1, out_cu);
}

// Round 4
// 125.991 us; speedup vs baseline: 1.4866x; 1.0292x over previous
//
#include <hip/hip_runtime.h>
#include <math.h>

// Problem constants
#define NT 320
#define NS 16
#define PIN 8
#define MOUT 8
// step = TMAX/(NT-1)
#define STEPF (1.0f/319.0f)

// ---------------------------------------------------------------------------
// Phase 1 (fused build_A + expm): 320 blocks x 256 thr.  Every block
// redundantly rebuilds A (16x16) from V1r/V2r/V3r (cheap, fully parallel,
// saves a launch + global round-trip), then computes E_k = expm(A * t_k)
// via scaling-and-squaring + Taylor-12 Horner (theta=0.25, rem ~1e-18).
// Emits CE_k = C E_k (8x16), Mrow_k = CE_k cov0 (8x16), G_k = CE_k B (8x8),
// y1_k = CE_k x0 (8).
// ---------------------------------------------------------------------------
__global__ void k_phase1(const float* __restrict__ V1r,
                         const float* __restrict__ V2r,
                         const float* __restrict__ V3r,
                         const float* __restrict__ C_w,
                         const float* __restrict__ B_w,
                         const float* __restrict__ cov0,
                         const float* __restrict__ x0,
                         float* __restrict__ CE_g,
                         float* __restrict__ Mrow_g,
                         float* __restrict__ G_g,
                         float* __restrict__ y1_g) {
    __shared__ float M[16][16];      // V1-lower, then reused as A
    __shared__ float Minv[16][16];
    __shared__ float Pinv[16][16];
    __shared__ float W[16][16];
    __shared__ float V2s[16][16];
    __shared__ float Bs[16][16];     // scaled A
    __shared__ float P[16][16];      // Horner/squaring state
    __shared__ float Cs[8][16];
    __shared__ float Bw[16][8];
    __shared__ float cov[16][16];
    __shared__ float x0s[16];
    __shared__ float CEs[8][16];
    __shared__ float rowsum[16];
    __shared__ float normA_s;
    const int tid = threadIdx.x;
    const int i = tid >> 4, j = tid & 15;
    const int k = blockIdx.x;
    const float t = (float)k * STEPF;

    // stage small operands
    cov[i][j] = cov0[tid];
    if (tid < 128) Cs[tid >> 4][tid & 15] = C_w[tid];
    if (tid < 128) Bw[tid >> 3][tid & 7]  = B_w[tid];
    if (tid < 16)  x0s[tid] = x0[tid];

    // --- build A ---
    float v;
    if (i > j)       v = V1r[i * 16 + j];
    else if (i == j) v = fabsf(V1r[i * 16 + i]) + 2.0f * 1e-3f;  // eps applied twice
    else             v = 0.0f;
    M[i][j]   = v;
    V2s[i][j] = (j <= i) ? V2r[i * 16 + j] : 0.0f;
    __syncthreads();

    if (tid < 16) {  // forward substitution, column tid (V1 lower-triangular)
        const int c = tid;
        float x[16];
        for (int r = 0; r < 16; ++r) {
            if (r < c) { x[r] = 0.0f; continue; }
            float s = (r == c) ? 1.0f : 0.0f;
            for (int kk = c; kk < r; ++kk) s -= M[r][kk] * x[kk];
            x[r] = s / M[r][r];
        }
        for (int r = 0; r < 16; ++r) Minv[r][c] = x[r];
    }
    __syncthreads();

    {   // P_inv = Minv^T Minv
        float acc = 0.0f;
#pragma unroll
        for (int kk = 0; kk < 16; ++kk) acc += Minv[kk][i] * Minv[kk][j];
        Pinv[i][j] = acc;
    }
    {   // W = -0.5 V2 V2^T + V3 (V3 = triu(V3r,1) - triu^T)
        float acc = 0.0f;
#pragma unroll
        for (int kk = 0; kk < 16; ++kk) acc += V2s[i][kk] * V2s[j][kk];
        float v3 = 0.0f;
        if (j > i)      v3 =  V3r[i * 16 + j];
        else if (i > j) v3 = -V3r[j * 16 + i];
        W[i][j] = -0.5f * acc + v3;
    }
    __syncthreads();
    float a_ij;
    {   // A = P_inv @ W ; store into M (dead after substitution)
        float acc = 0.0f;
#pragma unroll
        for (int kk = 0; kk < 16; ++kk) acc += Pinv[i][kk] * W[kk][j];
        a_ij = acc;
        M[i][j] = acc;
    }
    __syncthreads();
    if (j == 0) {
        float r = 0.0f;
#pragma unroll
        for (int kk = 0; kk < 16; ++kk) r += fabsf(M[i][kk]);
        rowsum[i] = r;
    }
    __syncthreads();
    if (tid == 0) {
        float m = 0.0f;
        for (int kk = 0; kk < 16; ++kk) m = fmaxf(m, rowsum[kk]);
        normA_s = m;
    }
    __syncthreads();

    // --- expm: scaling so ||A t / 2^s||_inf <= 0.25 ---
    float nt = normA_s * t;
    int s = 0;
    while (nt > 0.25f && s < 30) { nt *= 0.5f; ++s; }
    const float scale = t * exp2f((float)(-s));
    Bs[i][j] = a_ij * scale;
    P[i][j]  = ((i == j) ? 1.0f : 0.0f) + a_ij * scale * (1.0f / 12.0f);
    __syncthreads();

    // Horner: E = I + B(I + B/2(I + ... (I + B/12)...))
    for (int d = 11; d >= 1; --d) {
        float acc = 0.0f;
#pragma unroll
        for (int kk = 0; kk < 16; ++kk) acc += Bs[i][kk] * P[kk][j];
        __syncthreads();
        P[i][j] = ((i == j) ? 1.0f : 0.0f) + acc / (float)d;
        __syncthreads();
    }
    // squarings
    for (int q = 0; q < s; ++q) {
        float acc = 0.0f;
#pragma unroll
        for (int kk = 0; kk < 16; ++kk) acc += P[i][kk] * P[kk][j];
        __syncthreads();
        P[i][j] = acc;
        __syncthreads();
    }

    // CE = C @ E  (8x16)
    if (tid < 128) {
        const int a8 = tid >> 4, jc = tid & 15;
        float acc = 0.0f;
#pragma unroll
        for (int kk = 0; kk < 16; ++kk) acc += Cs[a8][kk] * P[kk][jc];
        CEs[a8][jc] = acc;
        CE_g[k * 128 + tid] = acc;
    }
    __syncthreads();
    // Mrow = CE @ covar_x0  (8x16)
    if (tid < 128) {
        const int a8 = tid >> 4, l = tid & 15;
        float acc = 0.0f;
#pragma unroll
        for (int kk = 0; kk < 16; ++kk) acc += CEs[a8][kk] * cov[kk][l];
        Mrow_g[k * 128 + tid] = acc;
    }
    // G = CE @ B_w  (8x8)
    if (tid < 64) {
        const int a8 = tid >> 3, p = tid & 7;
        float acc = 0.0f;
#pragma unroll
        for (int kk = 0; kk < 16; ++kk) acc += CEs[a8][kk] * Bw[kk][p];
        G_g[k * 64 + tid] = acc;
    }
    // y1 = CE @ x0  (8)
    if (tid < 8) {
        float acc = 0.0f;
#pragma unroll
        for (int kk = 0; kk < 16; ++kk) acc += CEs[tid][kk] * x0s[kk];
        y1_g[k * 8 + tid] = acc;
    }
}

// ---------------------------------------------------------------------------
// Phase 2 (fused covar + mean): grid (21, 320) x 256 thr.
//  bx in [0,20): covar1 tile (16 j's) + covar_U slice for row i.
//  bx == 20:     mean_y row i (trapezoid conv, LDS tree-reduce).
// The 320 mean blocks hide under the 6400 write-bound covar blocks.
// ---------------------------------------------------------------------------
__global__ void k_phase2(const float* __restrict__ Mrow_g,
                         const float* __restrict__ CE_g,
                         const float* __restrict__ y1_g,
                         const float* __restrict__ G_g,
                         const float* __restrict__ U,
                         const float* __restrict__ dU,
                         const float* __restrict__ D_w,
                         float* __restrict__ out_c1,
                         float* __restrict__ out_cu,
                         float* __restrict__ out_mean) {
    const int bx  = blockIdx.x;   // 0..20
    const int i   = blockIdx.y;   // 0..319
    const int tid = threadIdx.x;

    if (bx < 20) {
        __shared__ float Mi[128];
        __shared__ float CEj[2048];
        const int jg = bx;
        if (tid < 128) Mi[tid] = Mrow_g[i * 128 + tid];
        for (int idx = tid; idx < 2048; idx += 256) CEj[idx] = CE_g[jg * 2048 + idx];
        __syncthreads();

        const int jj = tid >> 4;         // 0..15
        const int a  = (tid >> 1) & 7;   // 0..7
        const int bg = tid & 1;          // 0..1 (4 b's each)
        const float* mi = Mi + a * 16;
        const float* ce = CEj + jj * 128 + bg * 64;
        float r[4];
#pragma unroll
        for (int b = 0; b < 4; ++b) {
            float acc = 0.0f;
#pragma unroll
            for (int l = 0; l < 16; ++l) acc += mi[l] * ce[b * 16 + l];
            r[b] = acc;
        }
        const int j = jg * 16 + jj;
        float4* dst = (float4*)(out_c1 + ((size_t)(i * 320 + j)) * 64 + a * 8 + bg * 4);
        *dst = make_float4(r[0], r[1], r[2], r[3]);

        if (tid < 16) {
            const int jx = jg * 16 + tid;
            const float d = (float)(i - jx) * STEPF;
            out_cu[i * 320 + jx] = expf(-50.0f * d * d);  // LT=0.1 -> 1/(2 LT^2)=50
        }
    } else {
        __shared__ float part[256];
        const int m  = tid & 7;
        const int js = tid >> 3;          // 0..31
        float acc = 0.0f;
        if (i > 0) {
            for (int j = js; j <= i; j += 32) {
                const float w = ((j == 0) || (j == i)) ? 0.5f : 1.0f;
                const float4* Gr = (const float4*)(G_g + (i - j) * 64 + m * 8);
                const float4* Ur = (const float4*)(U + j * 8);
                const float4 g0 = Gr[0], g1 = Gr[1];
                const float4 u0 = Ur[0], u1 = Ur[1];
                float d = g0.x * u0.x + g0.y * u0.y + g0.z * u0.z + g0.w * u0.w
                        + g1.x * u1.x + g1.y * u1.y + g1.z * u1.z + g1.w * u1.w;
                acc += w * d;
            }
        }
        part[tid] = acc;
        __syncthreads();
#pragma unroll
        for (int off = 128; off >= 8; off >>= 1) {
            if (tid < off) part[tid] += part[tid + off];
            __syncthreads();
        }
        if (tid < 8) {
            float t3 = 0.0f;
#pragma unroll
            for (int p = 0; p < 8; ++p) t3 += D_w[tid * 8 + p] * dU[i * 8 + p];
            out_mean[i * 8 + tid] = y1_g[i * 8 + tid] + STEPF * part[tid] + t3;
        }
    }
}

// ---------------------------------------------------------------------------
extern "C" void kernel_launch(void* const* d_in, const int* in_sizes, int n_in,
                              void* d_out, int out_size, void* d_ws, size_t ws_size,
                              hipStream_t stream) {
    const float* V1r  = (const float*)d_in[0];
    const float* V2r  = (const float*)d_in[1];
    const float* V3r  = (const float*)d_in[2];
    const float* B_w  = (const float*)d_in[3];
    const float* C_w  = (const float*)d_in[4];
    const float* D_w  = (const float*)d_in[5];
    const float* x0   = (const float*)d_in[6];
    const float* cov0 = (const float*)d_in[7];
    const float* U    = (const float*)d_in[8];
    const float* dU   = (const float*)d_in[9];

    float* ws   = (float*)d_ws;
    float* CE   = ws;             // 320*128 = 40960
    float* Mrow = CE + 40960;     // 40960
    float* G    = Mrow + 40960;   // 320*64 = 20480
    float* y1   = G + 20480;      // 2560

    float* out      = (float*)d_out;
    float* out_mean = out;                      // 320*8
    float* out_c1   = out + 2560;               // 320*320*64
    float* out_cu   = out + 2560 + 320*320*64;  // 320*320

    k_phase1<<<NT, 256, 0, stream>>>(V1r, V2r, V3r, C_w, B_w, cov0, x0,
                                     CE, Mrow, G, y1);
    k_phase2<<<dim3(21, NT), 256, 0, stream>>>(Mrow, CE, y1, G, U, dU, D_w,
                                               out_c1, out_cu, out_mean);
}

// Round 5
// 121.405 us; speedup vs baseline: 1.5428x; 1.0378x over previous
//
#include <hip/hip_runtime.h>
#include <math.h>

// Problem constants
#define NT 320
#define NS 16
#define PIN 8
#define MOUT 8
// step = TMAX/(NT-1)
#define STEPF (1.0f/319.0f)

// ---------------------------------------------------------------------------
// Phase 1 (fused build_A + expm): 320 blocks x 256 thr.  Every block
// redundantly rebuilds A (16x16) from V1r/V2r/V3r (fully parallel, saves a
// launch + global round-trip), then E_k = expm(A * t_k) via scaling-squaring
// + Taylor-9 Horner (theta=0.5 -> remainder ~3e-10).  Ping-pong LDS buffers:
// 1 barrier per matmul round instead of 2.
// Emits CE_k = C E_k (8x16), Mrow_k = CE_k cov0 (8x16), G_k = CE_k B (8x8),
// y1_k = CE_k x0 (8).
// ---------------------------------------------------------------------------
__global__ void k_phase1(const float* __restrict__ V1r,
                         const float* __restrict__ V2r,
                         const float* __restrict__ V3r,
                         const float* __restrict__ C_w,
                         const float* __restrict__ B_w,
                         const float* __restrict__ cov0,
                         const float* __restrict__ x0,
                         float* __restrict__ CE_g,
                         float* __restrict__ Mrow_g,
                         float* __restrict__ G_g,
                         float* __restrict__ y1_g) {
    __shared__ float M[16][16];      // V1-lower, then reused as A
    __shared__ float Minv[16][16];
    __shared__ float Pinv[16][16];
    __shared__ float W[16][16];
    __shared__ float V2s[16][16];
    __shared__ float Bs[16][16];     // scaled A
    __shared__ float bufA[16][16];   // ping-pong state
    __shared__ float bufB[16][16];
    __shared__ float Cs[8][16];
    __shared__ float Bw[16][8];
    __shared__ float cov[16][16];
    __shared__ float x0s[16];
    __shared__ float CEs[8][16];
    __shared__ float rowsum[16];
    __shared__ float normA_s;
    const int tid = threadIdx.x;
    const int i = tid >> 4, j = tid & 15;
    const int k = blockIdx.x;
    const float t = (float)k * STEPF;

    // stage small operands
    cov[i][j] = cov0[tid];
    if (tid < 128) Cs[tid >> 4][tid & 15] = C_w[tid];
    if (tid < 128) Bw[tid >> 3][tid & 7]  = B_w[tid];
    if (tid < 16)  x0s[tid] = x0[tid];

    // --- build A ---
    float v;
    if (i > j)       v = V1r[i * 16 + j];
    else if (i == j) v = fabsf(V1r[i * 16 + i]) + 2.0f * 1e-3f;  // eps applied twice
    else             v = 0.0f;
    M[i][j]   = v;
    V2s[i][j] = (j <= i) ? V2r[i * 16 + j] : 0.0f;
    __syncthreads();

    if (tid < 16) {  // forward substitution, column tid (V1 lower-triangular)
        const int c = tid;
        float x[16];
        for (int r = 0; r < 16; ++r) {
            if (r < c) { x[r] = 0.0f; continue; }
            float s = (r == c) ? 1.0f : 0.0f;
            for (int kk = c; kk < r; ++kk) s -= M[r][kk] * x[kk];
            x[r] = s / M[r][r];
        }
        for (int r = 0; r < 16; ++r) Minv[r][c] = x[r];
    }
    __syncthreads();

    {   // P_inv = Minv^T Minv
        float acc = 0.0f;
#pragma unroll
        for (int kk = 0; kk < 16; ++kk) acc += Minv[kk][i] * Minv[kk][j];
        Pinv[i][j] = acc;
    }
    {   // W = -0.5 V2 V2^T + V3 (V3 = triu(V3r,1) - triu^T)
        float acc = 0.0f;
#pragma unroll
        for (int kk = 0; kk < 16; ++kk) acc += V2s[i][kk] * V2s[j][kk];
        float v3 = 0.0f;
        if (j > i)      v3 =  V3r[i * 16 + j];
        else if (i > j) v3 = -V3r[j * 16 + i];
        W[i][j] = -0.5f * acc + v3;
    }
    __syncthreads();
    float a_ij;
    {   // A = P_inv @ W ; store into M (dead after substitution)
        float acc = 0.0f;
#pragma unroll
        for (int kk = 0; kk < 16; ++kk) acc += Pinv[i][kk] * W[kk][j];
        a_ij = acc;
        M[i][j] = acc;
    }
    __syncthreads();
    if (j == 0) {
        float r = 0.0f;
#pragma unroll
        for (int kk = 0; kk < 16; ++kk) r += fabsf(M[i][kk]);
        rowsum[i] = r;
    }
    __syncthreads();
    if (tid == 0) {
        float m = 0.0f;
        for (int kk = 0; kk < 16; ++kk) m = fmaxf(m, rowsum[kk]);
        normA_s = m;
    }
    __syncthreads();

    // --- expm: scaling so ||A t / 2^s||_inf <= 0.5 ---
    float nt = normA_s * t;
    int s = 0;
    while (nt > 0.5f && s < 30) { nt *= 0.5f; ++s; }
    const float scale = t * exp2f((float)(-s));
    Bs[i][j]   = a_ij * scale;
    bufA[i][j] = ((i == j) ? 1.0f : 0.0f) + a_ij * scale * (1.0f / 9.0f);
    __syncthreads();

    // Horner: E = I + B(I + B/2(I + ... (I + B/9)...)), ping-pong buffers,
    // one barrier per round (src-read completes before the barrier that
    // precedes any dst-write of the NEXT round).
    float (*src)[16] = bufA;
    float (*dst)[16] = bufB;
    for (int d = 8; d >= 1; --d) {
        float acc = 0.0f;
#pragma unroll
        for (int kk = 0; kk < 16; ++kk) acc += Bs[i][kk] * src[kk][j];
        dst[i][j] = ((i == j) ? 1.0f : 0.0f) + acc / (float)d;
        __syncthreads();
        float (*tmp)[16] = src; src = dst; dst = tmp;
    }
    // squarings (state in src)
    for (int q = 0; q < s; ++q) {
        float acc = 0.0f;
#pragma unroll
        for (int kk = 0; kk < 16; ++kk) acc += src[i][kk] * src[kk][j];
        dst[i][j] = acc;
        __syncthreads();
        float (*tmp)[16] = src; src = dst; dst = tmp;
    }

    // CE = C @ E  (8x16)
    if (tid < 128) {
        const int a8 = tid >> 4, jc = tid & 15;
        float acc = 0.0f;
#pragma unroll
        for (int kk = 0; kk < 16; ++kk) acc += Cs[a8][kk] * src[kk][jc];
        CEs[a8][jc] = acc;
        CE_g[k * 128 + tid] = acc;
    }
    __syncthreads();
    // Mrow = CE @ covar_x0  (8x16)
    if (tid < 128) {
        const int a8 = tid >> 4, l = tid & 15;
        float acc = 0.0f;
#pragma unroll
        for (int kk = 0; kk < 16; ++kk) acc += CEs[a8][kk] * cov[kk][l];
        Mrow_g[k * 128 + tid] = acc;
    }
    // G = CE @ B_w  (8x8)
    if (tid < 64) {
        const int a8 = tid >> 3, p = tid & 7;
        float acc = 0.0f;
#pragma unroll
        for (int kk = 0; kk < 16; ++kk) acc += CEs[a8][kk] * Bw[kk][p];
        G_g[k * 64 + tid] = acc;
    }
    // y1 = CE @ x0  (8)
    if (tid < 8) {
        float acc = 0.0f;
#pragma unroll
        for (int kk = 0; kk < 16; ++kk) acc += CEs[tid][kk] * x0s[kk];
        y1_g[k * 8 + tid] = acc;
    }
}

// ---------------------------------------------------------------------------
// Phase 2 (fused covar + mean): grid (21, 320) x 256 thr.
//  bx in [0,20): covar1 tile (16 j's) + covar_U slice for row i.
//  bx == 20:     mean_y row i (trapezoid conv, LDS tree-reduce).
// float4-vectorized LDS staging (2 dwordx4 per thread instead of 8 scalars).
// ---------------------------------------------------------------------------
__global__ void k_phase2(const float* __restrict__ Mrow_g,
                         const float* __restrict__ CE_g,
                         const float* __restrict__ y1_g,
                         const float* __restrict__ G_g,
                         const float* __restrict__ U,
                         const float* __restrict__ dU,
                         const float* __restrict__ D_w,
                         float* __restrict__ out_c1,
                         float* __restrict__ out_cu,
                         float* __restrict__ out_mean) {
    const int bx  = blockIdx.x;   // 0..20
    const int i   = blockIdx.y;   // 0..319
    const int tid = threadIdx.x;

    if (bx < 20) {
        __shared__ float Mi[128];
        __shared__ float CEj[2048];
        const int jg = bx;
        {   // vectorized staging: CEj = 512 float4, Mi = 32 float4
            const float4* srcC = (const float4*)(CE_g + jg * 2048);
            float4* dstC = (float4*)CEj;
            dstC[tid]       = srcC[tid];
            dstC[tid + 256] = srcC[tid + 256];
            if (tid < 32) ((float4*)Mi)[tid] = ((const float4*)(Mrow_g + i * 128))[tid];
        }
        __syncthreads();

        const int jj = tid >> 4;         // 0..15
        const int a  = (tid >> 1) & 7;   // 0..7
        const int bg = tid & 1;          // 0..1 (4 b's each)
        const float* mi = Mi + a * 16;
        const float* ce = CEj + jj * 128 + bg * 64;
        float r[4];
#pragma unroll
        for (int b = 0; b < 4; ++b) {
            float acc = 0.0f;
#pragma unroll
            for (int l = 0; l < 16; ++l) acc += mi[l] * ce[b * 16 + l];
            r[b] = acc;
        }
        const int j = jg * 16 + jj;
        float4* dst = (float4*)(out_c1 + ((size_t)(i * 320 + j)) * 64 + a * 8 + bg * 4);
        *dst = make_float4(r[0], r[1], r[2], r[3]);

        if (tid < 16) {
            const int jx = jg * 16 + tid;
            const float d = (float)(i - jx) * STEPF;
            out_cu[i * 320 + jx] = expf(-50.0f * d * d);  // LT=0.1 -> 1/(2 LT^2)=50
        }
    } else {
        __shared__ float part[256];
        const int m  = tid & 7;
        const int js = tid >> 3;          // 0..31
        float acc = 0.0f;
        if (i > 0) {
            for (int j = js; j <= i; j += 32) {
                const float w = ((j == 0) || (j == i)) ? 0.5f : 1.0f;
                const float4* Gr = (const float4*)(G_g + (i - j) * 64 + m * 8);
                const float4* Ur = (const float4*)(U + j * 8);
                const float4 g0 = Gr[0], g1 = Gr[1];
                const float4 u0 = Ur[0], u1 = Ur[1];
                float d = g0.x * u0.x + g0.y * u0.y + g0.z * u0.z + g0.w * u0.w
                        + g1.x * u1.x + g1.y * u1.y + g1.z * u1.z + g1.w * u1.w;
                acc += w * d;
            }
        }
        part[tid] = acc;
        __syncthreads();
#pragma unroll
        for (int off = 128; off >= 8; off >>= 1) {
            if (tid < off) part[tid] += part[tid + off];
            __syncthreads();
        }
        if (tid < 8) {
            float t3 = 0.0f;
#pragma unroll
            for (int p = 0; p < 8; ++p) t3 += D_w[tid * 8 + p] * dU[i * 8 + p];
            out_mean[i * 8 + tid] = y1_g[i * 8 + tid] + STEPF * part[tid] + t3;
        }
    }
}

// ---------------------------------------------------------------------------
extern "C" void kernel_launch(void* const* d_in, const int* in_sizes, int n_in,
                              void* d_out, int out_size, void* d_ws, size_t ws_size,
                              hipStream_t stream) {
    const float* V1r  = (const float*)d_in[0];
    const float* V2r  = (const float*)d_in[1];
    const float* V3r  = (const float*)d_in[2];
    const float* B_w  = (const float*)d_in[3];
    const float* C_w  = (const float*)d_in[4];
    const float* D_w  = (const float*)d_in[5];
    const float* x0   = (const float*)d_in[6];
    const float* cov0 = (const float*)d_in[7];
    const float* U    = (const float*)d_in[8];
    const float* dU   = (const float*)d_in[9];

    float* ws   = (float*)d_ws;
    float* CE   = ws;             // 320*128 = 40960
    float* Mrow = CE + 40960;     // 40960
    float* G    = Mrow + 40960;   // 320*64 = 20480
    float* y1   = G + 20480;      // 2560

    float* out      = (float*)d_out;
    float* out_mean = out;                      // 320*8
    float* out_c1   = out + 2560;               // 320*320*64
    float* out_cu   = out + 2560 + 320*320*64;  // 320*320

    k_phase1<<<NT, 256, 0, stream>>>(V1r, V2r, V3r, C_w, B_w, cov0, x0,
                                     CE, Mrow, G, y1);
    k_phase2<<<dim3(21, NT), 256, 0, stream>>>(Mrow, CE, y1, G, U, dU, D_w,
                                               out_c1, out_cu, out_mean);
}